// Round 4
// baseline (220.775 us; speedup 1.0000x reference)
//
#include <hip/hip_runtime.h>

#define N_PTS    20000
#define M_NODES  1024
#define BATCH    4
#define K_NN     50
#define D_MODEL  256
#define NPF      84      // num_pos_feats
#define BLOCK    512
#define NWAVE    (BLOCK / 64)
#define CAP      768     // survivor buffer capacity
#define NSMP     256     // sample count for threshold
#define RANK_T   3       // use 4th-smallest sample (E[survivors] ~ 311)

__device__ __forceinline__ float signed_angle(float ax, float ay, float az,
                                              float bx, float by, float bz) {
    float cx = ay * bz - az * by;
    float cy = az * bx - ax * bz;
    float cz = ax * by - ay * bx;
    float s = sqrtf(cx * cx + cy * cy + cz * cz);
    float c = ax * bx + ay * by + az * bz;
    float a = atan2f(s, c);
    return (c < 0.0f) ? -a : a;
}

__global__ __launch_bounds__(BLOCK) void ppf_kernel(
    const float* __restrict__ points,   // (B,N,3)
    const float* __restrict__ nodes,    // (B,M,3)
    const float* __restrict__ pnrm,     // (B,N,3)
    const float* __restrict__ nnrm,     // (B,M,3)
    const float* __restrict__ W,        // (4,256) row-major
    const float* __restrict__ bias,     // (256)
    float* __restrict__ out)            // glob (B,M,256) ++ pos (B,M,256)
{
    __shared__ unsigned long long skey[CAP];   // (d2bits<<32)|idx
    __shared__ unsigned int smp[NSMP];
    __shared__ int selidx[K_NN];
    __shared__ float f4[K_NN][4];
    __shared__ int red[NWAVE];
    __shared__ unsigned int s_t;
    __shared__ int s_pos;

    const int bm   = blockIdx.x;
    const int b    = bm >> 10;          // / M_NODES
    const int tid  = threadIdx.x;
    const int lane = tid & 63;

    const float* pts = points + (size_t)b * N_PTS * 3;
    const float* pnr = pnrm   + (size_t)b * N_PTS * 3;

    const float nx  = nodes[(size_t)bm * 3 + 0];
    const float ny  = nodes[(size_t)bm * 3 + 1];
    const float nz  = nodes[(size_t)bm * 3 + 2];
    const float n1x = nnrm[(size_t)bm * 3 + 0];
    const float n1y = nnrm[(size_t)bm * 3 + 1];
    const float n1z = nnrm[(size_t)bm * 3 + 2];

    // exact squared-distance bits (d2 >= 0 so IEEE bits are order-monotone)
    auto d2bits = [&](int i) -> unsigned int {
        float dx = pts[i * 3 + 0] - nx;
        float dy = pts[i * 3 + 1] - ny;
        float dz = pts[i * 3 + 2] - nz;
        return __float_as_uint(dx * dx + dy * dy + dz * dz);
    };

    // full recount of keys < t (fallback path only); uniform flow
    auto count_exact = [&](unsigned int t) -> int {
        int c = 0;
        for (int i = tid; i < N_PTS; i += BLOCK) c += (int)(d2bits(i) < t);
        for (int off = 32; off > 0; off >>= 1) c += __shfl_down(c, off);
        if (lane == 0) red[tid >> 6] = c;
        __syncthreads();
        int total = 0;
        #pragma unroll
        for (int w = 0; w < NWAVE; ++w) total += red[w];
        __syncthreads();
        return total;
    };

    // fused distance + ballot-compaction of survivors (keys < t); returns raw count
    auto compact = [&](unsigned int t) -> int {
        __syncthreads();
        if (tid == 0) s_pos = 0;
        __syncthreads();
        for (int i = tid; i < N_PTS; i += BLOCK) {
            unsigned int kb = d2bits(i);
            bool pred = kb < t;
            unsigned long long mask = __ballot(pred);
            if (mask) {
                int base = 0;
                if (lane == 0) base = atomicAdd(&s_pos, (int)__popcll(mask));
                base = __shfl(base, 0);
                if (pred) {
                    int p = base + (int)__popcll(mask & ((1ull << lane) - 1ull));
                    if (p < CAP)
                        skey[p] = ((unsigned long long)kb << 32) | (unsigned int)i;
                }
            }
        }
        __syncthreads();
        return s_pos;
    };

    // defense-in-depth: no wild reads even in pathological tie cases
    if (tid < K_NN) selidx[tid] = 0;

    // ---- Phase S: sampled threshold (exact f32-bit keys) ----
    if (tid < NSMP) smp[tid] = d2bits(tid * 78 + 17);   // max idx 19907
    __syncthreads();
    if (tid < NSMP) {
        unsigned int v = smp[tid];
        int rank = 0;
        for (int j = 0; j < NSMP; ++j) {
            unsigned int u = smp[j];
            rank += (int)((u < v) || (u == v && j < tid));
        }
        if (rank == RANK_T) s_t = v;
    }
    __syncthreads();

    // ---- Phase C: one fused scan+compact; fallback via full binary search ----
    unsigned int t = s_t;
    int total = compact(t);
    if (total < K_NN || total > CAP) {
        unsigned int lo = (total < K_NN) ? t : 0u;          // count(<lo) < K
        unsigned int hi = (total < K_NN) ? 0x7F800000u : t; // count(<hi) > CAP
        for (int it = 0; it < 34; ++it) {
            if (hi - lo <= 1u) { t = hi; break; }
            unsigned int mid = lo + ((hi - lo) >> 1);
            int c = count_exact(mid);
            if (c >= K_NN && c <= CAP) { t = mid; break; }
            if (c < K_NN) lo = mid; else hi = mid;
        }
        total = compact(t);
    }
    int nsurv = total < CAP ? total : CAP;

    // ---- Phase E: exact rank selection of the 50 nearest (ties -> low idx) ----
    for (int s = tid; s < nsurv; s += BLOCK) {
        unsigned long long mykey = skey[s];
        int rank = 0;
        for (int j = 0; j < nsurv; ++j) rank += (int)(skey[j] < mykey);
        if (rank < K_NN) selidx[rank] = (int)(mykey & 0xFFFFFFFFull);
    }
    __syncthreads();

    // ---- Phase F: PPF features for the 50 selected neighbors ----
    if (tid < K_NN) {
        int i = selidx[tid];
        float px = pts[i * 3 + 0], py = pts[i * 3 + 1], pz = pts[i * 3 + 2];
        float qx = pnr[i * 3 + 0], qy = pnr[i * 3 + 1], qz = pnr[i * 3 + 2];
        float ijx = px - nx, ijy = py - ny, ijz = pz - nz;
        float d = sqrtf(ijx * ijx + ijy * ijy + ijz * ijz);  // SCALE = 1
        float a1 = signed_angle(ijx, ijy, ijz, n1x, n1y, n1z);
        float a2 = signed_angle(-ijx, -ijy, -ijz, qx, qy, qz);
        float a3 = signed_angle(n1x, n1y, n1z, qx, qy, qz);
        f4[tid][0] = d;
        f4[tid][1] = a1;
        f4[tid][2] = a2;
        f4[tid][3] = a3;
    }
    __syncthreads();

    // ---- Phase G (tid<256): glob ---- Phase H (tid>=256): pos emb ----
    if (tid < D_MODEL) {
        int d = tid;
        float w0 = W[d], w1 = W[D_MODEL + d], w2 = W[2 * D_MODEL + d], w3 = W[3 * D_MODEL + d];
        float mx = -INFINITY;
        #pragma unroll 5
        for (int k = 0; k < K_NN; ++k) {
            float v = f4[k][0] * w0 + f4[k][1] * w1 + f4[k][2] * w2 + f4[k][3] * w3;
            mx = fmaxf(mx, v);
        }
        out[(size_t)bm * D_MODEL + d] = mx + bias[d];
    } else {
        int d = tid - D_MODEL;
        float v = 0.0f;
        if (d < 3 * NPF) {
            int c = d / NPF;
            int r = d - c * NPF;
            int i = r >> 1;
            float nc = (c == 0) ? nx : ((c == 1) ? ny : nz);
            const float L2_10000 = 13.287712379549449f;  // log2(10000)
            float tinv = exp2f(-L2_10000 * (float)i / 42.0f);
            float x = nc * tinv;
            v = (r & 1) ? cosf(x) : sinf(x);
        }
        out[(size_t)BATCH * M_NODES * D_MODEL + (size_t)bm * D_MODEL + d] = v;
    }
}

extern "C" void kernel_launch(void* const* d_in, const int* in_sizes, int n_in,
                              void* d_out, int out_size, void* d_ws, size_t ws_size,
                              hipStream_t stream) {
    const float* points = (const float*)d_in[0];
    const float* nodes  = (const float*)d_in[1];
    const float* pn     = (const float*)d_in[2];
    const float* nn     = (const float*)d_in[3];
    const float* W      = (const float*)d_in[4];
    const float* bias   = (const float*)d_in[5];
    float* out = (float*)d_out;

    dim3 grid(BATCH * M_NODES);
    dim3 block(BLOCK);
    ppf_kernel<<<grid, block, 0, stream>>>(points, nodes, pn, nn, W, bias, out);
}

// Round 5
// 148.122 us; speedup vs baseline: 1.4905x; 1.4905x over previous
//
#include <hip/hip_runtime.h>

#define N_PTS    20000
#define M_NODES  1024
#define BATCH    4
#define NNODE    (BATCH * M_NODES)   // 4096
#define K_NN     50
#define D_MODEL  256
#define NPF      84
#define CAP      768                 // ws candidate capacity per node
#define LCAP     1024                // LDS skey capacity (kernel C)
#define TN       16                  // nodes per block in kernel B
#define CHUNK    2560                // points per chunk in kernel B
#define NCHUNK   8                   // 8*2560 = 20480 >= 20000
#define PPT      10                  // points per thread (CHUNK/256)
#define WLO      26                  // sample-count window (of 2048 samples)
#define WHI      50

__device__ __forceinline__ float signed_angle(float ax, float ay, float az,
                                              float bx, float by, float bz) {
    float cx = ay * bz - az * by;
    float cy = az * bx - ax * bz;
    float cz = ax * by - ay * bx;
    float s = sqrtf(cx * cx + cy * cy + cz * cz);
    float c = ax * bx + ay * by + az * bz;
    float a = atan2f(s, c);
    return (c < 0.0f) ? -a : a;
}

// ============ Kernel A: per-node threshold from 2048 samples + pos_emb ============
__global__ __launch_bounds__(256) void ka_thresh(
    const float* __restrict__ points, const float* __restrict__ nodes,
    float* __restrict__ tws, int* __restrict__ gcount, float* __restrict__ out)
{
    __shared__ int red[4];
    const int bm = blockIdx.x, b = bm >> 10, tid = threadIdx.x, lane = tid & 63;
    const float* pts = points + (size_t)b * N_PTS * 3;
    const float nx = nodes[(size_t)bm * 3 + 0];
    const float ny = nodes[(size_t)bm * 3 + 1];
    const float nz = nodes[(size_t)bm * 3 + 2];

    // 8 samples/thread from the first 2048 points (i.i.d. data -> unbiased)
    unsigned k[8];
    #pragma unroll
    for (int s = 0; s < 8; ++s) {
        int j = s * 256 + tid;
        float dx = pts[j * 3 + 0] - nx;
        float dy = pts[j * 3 + 1] - ny;
        float dz = pts[j * 3 + 2] - nz;
        k[s] = __float_as_uint(dx * dx + dy * dy + dz * dz) >> 16;
    }
    unsigned lo = 0, hi = 0x7F81u, v = 0;
    for (int it = 0; it < 16; ++it) {                 // fixed count: uniform flow
        unsigned mid = lo + ((hi - lo) >> 1);
        int c = 0;
        #pragma unroll
        for (int s = 0; s < 8; ++s) c += (int)(k[s] < mid);
        for (int off = 32; off > 0; off >>= 1) c += __shfl_down(c, off);
        if (lane == 0) red[tid >> 6] = c;
        __syncthreads();
        c = red[0] + red[1] + red[2] + red[3];
        __syncthreads();
        if (v == 0) {
            if (c >= WLO && c <= WHI) v = mid;
            else if (c < WLO) lo = mid;
            else hi = mid;
            if (hi - lo <= 1u && v == 0) v = hi;
        }
    }
    if (v == 0) v = hi;
    if (tid == 0) { tws[bm] = __uint_as_float(v << 16); gcount[bm] = 0; }

    // pos_emb (validated formula from round 4)
    {
        int d = tid;
        float pv = 0.0f;
        if (d < 3 * NPF) {
            int c = d / NPF, r = d - c * NPF, i = r >> 1;
            float nc = (c == 0) ? nx : ((c == 1) ? ny : nz);
            const float L2_10000 = 13.287712379549449f;
            float tinv = exp2f(-L2_10000 * (float)i / 42.0f);
            float x = nc * tinv;
            pv = (r & 1) ? cosf(x) : sinf(x);
        }
        out[(size_t)NNODE * D_MODEL + (size_t)bm * D_MODEL + d] = pv;
    }
}

// ============ Kernel B: tiled scan, append survivors per node ============
__global__ __launch_bounds__(256) void kb_scan(
    const float* __restrict__ points, const float* __restrict__ nodes,
    const float* __restrict__ tws, int* __restrict__ gcount,
    unsigned short* __restrict__ cand)
{
    __shared__ float4 snd[TN];
    const int tile = blockIdx.x;          // 0..255
    const int ch   = blockIdx.y;          // 0..7
    const int ngb  = tile * TN;           // global node base
    const int b    = ngb >> 10;
    const int tid  = threadIdx.x, lane = tid & 63;
    const float* pts = points + (size_t)b * N_PTS * 3;

    if (tid < TN) {
        int ng = ngb + tid;
        snd[tid] = make_float4(nodes[(size_t)ng * 3 + 0], nodes[(size_t)ng * 3 + 1],
                               nodes[(size_t)ng * 3 + 2], tws[ng]);
    }
    __syncthreads();

    const int base0 = ch * CHUNK;
    float px[PPT], py[PPT], pz[PPT];
    #pragma unroll
    for (int p = 0; p < PPT; ++p) {
        int j = base0 + p * 256 + tid;
        bool ok = j < N_PTS;
        int jj = ok ? j : 0;
        float vx = pts[jj * 3 + 0], vy = pts[jj * 3 + 1], vz = pts[jj * 3 + 2];
        px[p] = ok ? vx : 1e18f;
        py[p] = ok ? vy : 1e18f;
        pz[p] = ok ? vz : 1e18f;
    }

    for (int n = 0; n < TN; ++n) {
        float4 nd = snd[n];
        unsigned m = 0;
        #pragma unroll
        for (int p = 0; p < PPT; ++p) {
            float dx = px[p] - nd.x, dy = py[p] - nd.y, dz = pz[p] - nd.z;
            float d2 = dx * dx + dy * dy + dz * dz;
            m |= (d2 < nd.w) ? (1u << p) : 0u;
        }
        int cnt = __popc(m);
        int inc = cnt;
        #pragma unroll
        for (int s = 1; s < 64; s <<= 1) {
            int u = __shfl_up(inc, s);
            if (lane >= s) inc += u;
        }
        int wtot = __shfl(inc, 63);
        if (wtot) {
            int basew = 0;
            if (lane == 63) basew = atomicAdd(&gcount[ngb + n], wtot);
            basew = __shfl(basew, 63);
            int w = basew + inc - cnt;
            unsigned mm = m;
            while (mm) {
                int p = __ffs(mm) - 1; mm &= mm - 1;
                if (w < CAP)
                    cand[(size_t)(ngb + n) * CAP + w] =
                        (unsigned short)(base0 + p * 256 + tid);
                ++w;
            }
        }
    }
}

// ============ Kernel C: exact top-50 select + PPF features + projection ============
__global__ __launch_bounds__(256) void kc_select(
    const float* __restrict__ points, const float* __restrict__ nodes,
    const float* __restrict__ pnrm, const float* __restrict__ nnrm,
    const float* __restrict__ W, const float* __restrict__ bias,
    const float* __restrict__ tws, const int* __restrict__ gcount,
    const unsigned short* __restrict__ cand, float* __restrict__ out)
{
    __shared__ unsigned long long skey[LCAP];
    __shared__ int red[4];
    __shared__ int selidx[K_NN];
    __shared__ float f4[K_NN][4];
    __shared__ int s_pos;

    const int bm = blockIdx.x, b = bm >> 10, tid = threadIdx.x, lane = tid & 63;
    const float* pts = points + (size_t)b * N_PTS * 3;
    const float* pnr = pnrm   + (size_t)b * N_PTS * 3;
    const float nx  = nodes[(size_t)bm * 3 + 0];
    const float ny  = nodes[(size_t)bm * 3 + 1];
    const float nz  = nodes[(size_t)bm * 3 + 2];
    const float n1x = nnrm[(size_t)bm * 3 + 0];
    const float n1y = nnrm[(size_t)bm * 3 + 1];
    const float n1z = nnrm[(size_t)bm * 3 + 2];

    auto d2bits = [&](int i) -> unsigned int {
        float dx = pts[i * 3 + 0] - nx;
        float dy = pts[i * 3 + 1] - ny;
        float dz = pts[i * 3 + 2] - nz;
        return __float_as_uint(dx * dx + dy * dy + dz * dz);
    };
    auto countb = [&](unsigned tb) -> int {
        float tf = __uint_as_float(tb);
        int c = 0;
        for (int i = tid; i < N_PTS; i += 256) {
            float dx = pts[i * 3 + 0] - nx;
            float dy = pts[i * 3 + 1] - ny;
            float dz = pts[i * 3 + 2] - nz;
            c += (int)(dx * dx + dy * dy + dz * dz < tf);
        }
        for (int off = 32; off > 0; off >>= 1) c += __shfl_down(c, off);
        if (lane == 0) red[tid >> 6] = c;
        __syncthreads();
        int total = red[0] + red[1] + red[2] + red[3];
        __syncthreads();
        return total;
    };

    if (tid < K_NN) selidx[tid] = 0;   // defense vs pathological ties

    int cnt = gcount[bm];              // EXACT survivor count (atomics past cap)
    int nsurv;
    if (cnt >= K_NN && cnt <= CAP) {
        // fast path: candidate set in ws is complete
        for (int s = tid; s < cnt; s += 256) {
            int i = (int)cand[(size_t)bm * CAP + s];
            skey[s] = ((unsigned long long)d2bits(i) << 32) | (unsigned int)i;
        }
        nsurv = cnt;
        __syncthreads();
    } else {
        // slow path (expected ~0 nodes): find usable threshold, recompact
        unsigned tb = __float_as_uint(tws[bm]);
        unsigned lo = 0, hi = 0x7F000000u, good = 0;
        bool haveLo = false, haveHi = false;
        if (cnt < K_NN) { lo = tb; haveLo = true; }
        else            { hi = tb; haveHi = true; }
        unsigned cur = tb;
        for (int a = 0; a < 40 && !good; ++a) {
            if (haveLo && !haveHi) {
                cur = (cur < 0x7E800000u) ? cur + 0x00800000u : 0x7F000000u;  // *2
            } else if (haveHi && !haveLo) {
                cur = (cur >= 0x00800000u) ? cur - 0x00800000u : (cur >> 1);  // /2
            } else {
                cur = lo + ((hi - lo) >> 1);
                if (hi - lo <= 1u) { good = hi; break; }
            }
            int c = countb(cur);
            if (c >= K_NN && c <= LCAP) good = cur;
            else if (c < K_NN) { lo = cur; haveLo = true; }
            else               { hi = cur; haveHi = true; }
        }
        if (!good) good = haveHi ? hi : 0x7F000000u;
        // ballot-compact into LDS
        __syncthreads();
        if (tid == 0) s_pos = 0;
        __syncthreads();
        float tf = __uint_as_float(good);
        for (int i = tid; i < N_PTS; i += 256) {
            unsigned kb = d2bits(i);
            bool pred = __uint_as_float(kb) < tf;
            unsigned long long mask = __ballot(pred);
            if (mask) {
                int basew = 0;
                if (lane == 0) basew = atomicAdd(&s_pos, (int)__popcll(mask));
                basew = __shfl(basew, 0);
                if (pred) {
                    int p = basew + (int)__popcll(mask & ((1ull << lane) - 1ull));
                    if (p < LCAP)
                        skey[p] = ((unsigned long long)kb << 32) | (unsigned int)i;
                }
            }
        }
        __syncthreads();
        nsurv = s_pos < LCAP ? s_pos : LCAP;
    }

    // exact rank selection of the 50 nearest (ties -> low idx)
    for (int s = tid; s < nsurv; s += 256) {
        unsigned long long mykey = skey[s];
        int rank = 0;
        for (int j = 0; j < nsurv; ++j) rank += (int)(skey[j] < mykey);
        if (rank < K_NN) selidx[rank] = (int)(mykey & 0xFFFFFFFFull);
    }
    __syncthreads();

    // PPF features
    if (tid < K_NN) {
        int i = selidx[tid];
        float pxx = pts[i * 3 + 0], pyy = pts[i * 3 + 1], pzz = pts[i * 3 + 2];
        float qx = pnr[i * 3 + 0], qy = pnr[i * 3 + 1], qz = pnr[i * 3 + 2];
        float ijx = pxx - nx, ijy = pyy - ny, ijz = pzz - nz;
        float d = sqrtf(ijx * ijx + ijy * ijy + ijz * ijz);
        f4[tid][0] = d;
        f4[tid][1] = signed_angle(ijx, ijy, ijz, n1x, n1y, n1z);
        f4[tid][2] = signed_angle(-ijx, -ijy, -ijz, qx, qy, qz);
        f4[tid][3] = signed_angle(n1x, n1y, n1z, qx, qy, qz);
    }
    __syncthreads();

    // glob[d] = max_k (f4[k] . W[:,d]) + b[d]
    {
        int d = tid;
        float w0 = W[d], w1 = W[D_MODEL + d], w2 = W[2 * D_MODEL + d], w3 = W[3 * D_MODEL + d];
        float mx = -INFINITY;
        #pragma unroll 5
        for (int k = 0; k < K_NN; ++k) {
            float v = f4[k][0] * w0 + f4[k][1] * w1 + f4[k][2] * w2 + f4[k][3] * w3;
            mx = fmaxf(mx, v);
        }
        out[(size_t)bm * D_MODEL + d] = mx + bias[d];
    }
}

extern "C" void kernel_launch(void* const* d_in, const int* in_sizes, int n_in,
                              void* d_out, int out_size, void* d_ws, size_t ws_size,
                              hipStream_t stream) {
    const float* points = (const float*)d_in[0];
    const float* nodes  = (const float*)d_in[1];
    const float* pn     = (const float*)d_in[2];
    const float* nn     = (const float*)d_in[3];
    const float* W      = (const float*)d_in[4];
    const float* bias   = (const float*)d_in[5];
    float* out = (float*)d_out;

    // ws layout: tws f32[4096] @0 ; gcount i32[4096] @16K ; cand u16[4096*768] @32K
    char* ws = (char*)d_ws;
    float* tws = (float*)ws;
    int* gcount = (int*)(ws + 16384);
    unsigned short* cand = (unsigned short*)(ws + 32768);

    ka_thresh<<<dim3(NNODE), dim3(256), 0, stream>>>(points, nodes, tws, gcount, out);
    kb_scan<<<dim3(NNODE / TN, NCHUNK), dim3(256), 0, stream>>>(points, nodes, tws, gcount, cand);
    kc_select<<<dim3(NNODE), dim3(256), 0, stream>>>(points, nodes, pn, nn, W, bias,
                                                     tws, gcount, cand, out);
}

// Round 6
// 107.812 us; speedup vs baseline: 2.0478x; 1.3739x over previous
//
#include <hip/hip_runtime.h>

#define N_PTS    20000
#define M_NODES  1024
#define BATCH    4
#define NNODE    (BATCH * M_NODES)   // 4096
#define K_NN     50
#define D_MODEL  256
#define NPF      84
#define CAP      768                 // ws candidate capacity per node
#define SELWIN   256                 // refine target window upper bound
#define TN       16                  // nodes per block in kernel B
#define CHUNK    2560                // points per chunk in kernel B
#define NCHUNK   8                   // 8*2560 = 20480 >= 20000
#define PPT      10                  // points per thread (CHUNK/256)
#define WLO      26                  // sample-count window (of 2048 samples)
#define WHI      50

__device__ __forceinline__ float signed_angle(float ax, float ay, float az,
                                              float bx, float by, float bz) {
    float cx = ay * bz - az * by;
    float cy = az * bx - ax * bz;
    float cz = ax * by - ay * bx;
    float s = sqrtf(cx * cx + cy * cy + cz * cz);
    float c = ax * bx + ay * by + az * bz;
    float a = atan2f(s, c);
    return (c < 0.0f) ? -a : a;
}

// ============ Kernel A: per-node threshold from 2048 samples + pos_emb ============
__global__ __launch_bounds__(256) void ka_thresh(
    const float* __restrict__ points, const float* __restrict__ nodes,
    float* __restrict__ tws, int* __restrict__ gcount, float* __restrict__ out)
{
    __shared__ int red[4];
    const int bm = blockIdx.x, b = bm >> 10, tid = threadIdx.x, lane = tid & 63;
    const float* pts = points + (size_t)b * N_PTS * 3;
    const float nx = nodes[(size_t)bm * 3 + 0];
    const float ny = nodes[(size_t)bm * 3 + 1];
    const float nz = nodes[(size_t)bm * 3 + 2];

    unsigned k[8];
    #pragma unroll
    for (int s = 0; s < 8; ++s) {
        int j = s * 256 + tid;
        float dx = pts[j * 3 + 0] - nx;
        float dy = pts[j * 3 + 1] - ny;
        float dz = pts[j * 3 + 2] - nz;
        k[s] = __float_as_uint(dx * dx + dy * dy + dz * dz) >> 16;
    }
    unsigned lo = 0, hi = 0x7F81u, v = 0;
    for (int it = 0; it < 16; ++it) {                 // fixed count: uniform flow
        unsigned mid = lo + ((hi - lo) >> 1);
        int c = 0;
        #pragma unroll
        for (int s = 0; s < 8; ++s) c += (int)(k[s] < mid);
        for (int off = 32; off > 0; off >>= 1) c += __shfl_down(c, off);
        if (lane == 0) red[tid >> 6] = c;
        __syncthreads();
        c = red[0] + red[1] + red[2] + red[3];
        __syncthreads();
        if (v == 0) {
            if (c >= WLO && c <= WHI) v = mid;
            else if (c < WLO) lo = mid;
            else hi = mid;
            if (hi - lo <= 1u && v == 0) v = hi;
        }
    }
    if (v == 0) v = hi;
    if (tid == 0) { tws[bm] = __uint_as_float(v << 16); gcount[bm] = 0; }

    // pos_emb
    {
        int d = tid;
        float pv = 0.0f;
        if (d < 3 * NPF) {
            int c = d / NPF, r = d - c * NPF, i = r >> 1;
            float nc = (c == 0) ? nx : ((c == 1) ? ny : nz);
            const float L2_10000 = 13.287712379549449f;
            float tinv = exp2f(-L2_10000 * (float)i / 42.0f);
            float x = nc * tinv;
            pv = (r & 1) ? cosf(x) : sinf(x);
        }
        out[(size_t)NNODE * D_MODEL + (size_t)bm * D_MODEL + d] = pv;
    }
}

// ============ Kernel B: tiled scan, append survivors per node ============
__global__ __launch_bounds__(256) void kb_scan(
    const float* __restrict__ points, const float* __restrict__ nodes,
    const float* __restrict__ tws, int* __restrict__ gcount,
    unsigned short* __restrict__ cand)
{
    __shared__ float4 snd[TN];
    const int tile = blockIdx.x;
    const int ch   = blockIdx.y;
    const int ngb  = tile * TN;
    const int b    = ngb >> 10;
    const int tid  = threadIdx.x, lane = tid & 63;
    const float* pts = points + (size_t)b * N_PTS * 3;

    if (tid < TN) {
        int ng = ngb + tid;
        snd[tid] = make_float4(nodes[(size_t)ng * 3 + 0], nodes[(size_t)ng * 3 + 1],
                               nodes[(size_t)ng * 3 + 2], tws[ng]);
    }
    __syncthreads();

    const int base0 = ch * CHUNK;
    float px[PPT], py[PPT], pz[PPT];
    #pragma unroll
    for (int p = 0; p < PPT; ++p) {
        int j = base0 + p * 256 + tid;
        bool ok = j < N_PTS;
        int jj = ok ? j : 0;
        float vx = pts[jj * 3 + 0], vy = pts[jj * 3 + 1], vz = pts[jj * 3 + 2];
        px[p] = ok ? vx : 1e18f;
        py[p] = ok ? vy : 1e18f;
        pz[p] = ok ? vz : 1e18f;
    }

    for (int n = 0; n < TN; ++n) {
        float4 nd = snd[n];
        unsigned m = 0;
        #pragma unroll
        for (int p = 0; p < PPT; ++p) {
            float dx = px[p] - nd.x, dy = py[p] - nd.y, dz = pz[p] - nd.z;
            float d2 = dx * dx + dy * dy + dz * dz;
            m |= (d2 < nd.w) ? (1u << p) : 0u;
        }
        int cnt = __popc(m);
        int inc = cnt;
        #pragma unroll
        for (int s = 1; s < 64; s <<= 1) {
            int u = __shfl_up(inc, s);
            if (lane >= s) inc += u;
        }
        int wtot = __shfl(inc, 63);
        if (wtot) {
            int basew = 0;
            if (lane == 63) basew = atomicAdd(&gcount[ngb + n], wtot);
            basew = __shfl(basew, 63);
            int w = basew + inc - cnt;
            unsigned mm = m;
            while (mm) {
                int p = __ffs(mm) - 1; mm &= mm - 1;
                if (w < CAP)
                    cand[(size_t)(ngb + n) * CAP + w] =
                        (unsigned short)(base0 + p * 256 + tid);
                ++w;
            }
        }
    }
}

// ============ Kernel C: exact top-50 select + PPF features + projection ============
__global__ __launch_bounds__(256) void kc_select(
    const float* __restrict__ points, const float* __restrict__ nodes,
    const float* __restrict__ pnrm, const float* __restrict__ nnrm,
    const float* __restrict__ W, const float* __restrict__ bias,
    const float* __restrict__ tws, const int* __restrict__ gcount,
    const unsigned short* __restrict__ cand, float* __restrict__ out)
{
    __shared__ unsigned long long sel[CAP];   // refine result / fallback buffer
    __shared__ int red[4];
    __shared__ int selidx[K_NN];
    __shared__ float f4[K_NN][4];
    __shared__ int s_pos;

    const int bm = blockIdx.x, b = bm >> 10, tid = threadIdx.x, lane = tid & 63;
    const float* pts = points + (size_t)b * N_PTS * 3;
    const float* pnr = pnrm   + (size_t)b * N_PTS * 3;
    const float nx  = nodes[(size_t)bm * 3 + 0];
    const float ny  = nodes[(size_t)bm * 3 + 1];
    const float nz  = nodes[(size_t)bm * 3 + 2];
    const float n1x = nnrm[(size_t)bm * 3 + 0];
    const float n1y = nnrm[(size_t)bm * 3 + 1];
    const float n1z = nnrm[(size_t)bm * 3 + 2];

    auto d2bits = [&](int i) -> unsigned int {
        float dx = pts[i * 3 + 0] - nx;
        float dy = pts[i * 3 + 1] - ny;
        float dz = pts[i * 3 + 2] - nz;
        return __float_as_uint(dx * dx + dy * dy + dz * dz);
    };
    auto blockSum = [&](int c) -> int {
        for (int off = 32; off > 0; off >>= 1) c += __shfl_down(c, off);
        if (lane == 0) red[tid >> 6] = c;
        __syncthreads();
        int total = red[0] + red[1] + red[2] + red[3];
        __syncthreads();
        return total;
    };
    auto countb = [&](unsigned tb) -> int {     // global rescan (slow path only)
        float tf = __uint_as_float(tb);
        int c = 0;
        for (int i = tid; i < N_PTS; i += 256) {
            float dx = pts[i * 3 + 0] - nx;
            float dy = pts[i * 3 + 1] - ny;
            float dz = pts[i * 3 + 2] - nz;
            c += (int)(dx * dx + dy * dy + dz * dz < tf);
        }
        return blockSum(c);
    };

    if (tid < K_NN) selidx[tid] = 0;   // defense vs pathological ties

    const unsigned long long INVALID = ~0ull;
    int cnt = gcount[bm];              // EXACT survivor count
    int nsel = 0;

    if (cnt >= K_NN && cnt <= CAP) {
        // ---- fast path: keys in registers ----
        const unsigned short* cp = cand + (size_t)bm * CAP;
        unsigned long long k0 = INVALID, k1 = INVALID, k2 = INVALID;
        if (tid < cnt) {
            int i = (int)cp[tid];
            k0 = ((unsigned long long)d2bits(i) << 32) | (unsigned int)i;
        }
        if (tid + 256 < cnt) {
            int i = (int)cp[tid + 256];
            k1 = ((unsigned long long)d2bits(i) << 32) | (unsigned int)i;
        }
        if (tid + 512 < cnt) {
            int i = (int)cp[tid + 512];
            k2 = ((unsigned long long)d2bits(i) << 32) | (unsigned int)i;
        }

        // refine cut so that #selected in [K_NN, SELWIN]
        unsigned long long tcut = INVALID;
        bool conv = (cnt <= SELWIN);            // take-all if already small
        if (!conv) {
            unsigned lo = 0, hi = 0x7F800001u;
            for (int it = 0; it < 24 && !conv; ++it) {
                unsigned mid = lo + ((hi - lo) >> 1);
                unsigned long long tm = (unsigned long long)mid << 32;
                int c = (int)(k0 < tm) + (int)(k1 < tm) + (int)(k2 < tm);
                c = blockSum(c);
                if (c >= K_NN && c <= SELWIN) { tcut = tm; conv = true; }
                else if (c < K_NN) lo = mid;
                else hi = mid;
                if (hi - lo <= 1u) break;
            }
            // !conv (pathological ties): tcut stays INVALID -> select all, full rank
        }

        __syncthreads();
        if (tid == 0) s_pos = 0;
        __syncthreads();
        unsigned long long ks[3] = {k0, k1, k2};
        #pragma unroll
        for (int r = 0; r < 3; ++r) {
            bool p = ks[r] < tcut;
            unsigned long long mask = __ballot(p);
            if (mask) {
                int basew = 0;
                if (lane == 0) basew = atomicAdd(&s_pos, (int)__popcll(mask));
                basew = __shfl(basew, 0);
                if (p) {
                    int q = basew + (int)__popcll(mask & ((1ull << lane) - 1ull));
                    sel[q] = ks[r];   // q < cnt <= CAP always
                }
            }
        }
        __syncthreads();
        nsel = s_pos;
    } else {
        // ---- slow path (expected ~never): global threshold repair + compact ----
        unsigned tb = __float_as_uint(tws[bm]);
        unsigned lo = 0, hi = 0x7F000000u, good = 0;
        bool haveLo = false, haveHi = false;
        if (cnt < K_NN) { lo = tb; haveLo = true; }
        else            { hi = tb; haveHi = true; }
        unsigned cur = tb;
        for (int a = 0; a < 40 && !good; ++a) {
            if (haveLo && !haveHi) {
                cur = (cur < 0x7E800000u) ? cur + 0x00800000u : 0x7F000000u;
            } else if (haveHi && !haveLo) {
                cur = (cur >= 0x00800000u) ? cur - 0x00800000u : (cur >> 1);
            } else {
                cur = lo + ((hi - lo) >> 1);
                if (hi - lo <= 1u) { good = hi; break; }
            }
            int c = countb(cur);
            if (c >= K_NN && c <= CAP) good = cur;
            else if (c < K_NN) { lo = cur; haveLo = true; }
            else               { hi = cur; haveHi = true; }
        }
        if (!good) good = haveHi ? hi : 0x7F000000u;
        __syncthreads();
        if (tid == 0) s_pos = 0;
        __syncthreads();
        float tf = __uint_as_float(good);
        for (int i = tid; i < N_PTS; i += 256) {
            unsigned kb = d2bits(i);
            bool pred = __uint_as_float(kb) < tf;
            unsigned long long mask = __ballot(pred);
            if (mask) {
                int basew = 0;
                if (lane == 0) basew = atomicAdd(&s_pos, (int)__popcll(mask));
                basew = __shfl(basew, 0);
                if (pred) {
                    int q = basew + (int)__popcll(mask & ((1ull << lane) - 1ull));
                    if (q < CAP)
                        sel[q] = ((unsigned long long)kb << 32) | (unsigned int)i;
                }
            }
        }
        __syncthreads();
        nsel = s_pos < CAP ? s_pos : CAP;
    }

    // ---- exact rank selection of the 50 nearest (ties -> low idx) ----
    for (int s = tid; s < nsel; s += 256) {
        unsigned long long mykey = sel[s];
        int rank = 0;
        for (int j = 0; j < nsel; ++j) rank += (int)(sel[j] < mykey);
        if (rank < K_NN) selidx[rank] = (int)(mykey & 0xFFFFFFFFull);
    }
    __syncthreads();

    // ---- PPF features ----
    if (tid < K_NN) {
        int i = selidx[tid];
        float pxx = pts[i * 3 + 0], pyy = pts[i * 3 + 1], pzz = pts[i * 3 + 2];
        float qx = pnr[i * 3 + 0], qy = pnr[i * 3 + 1], qz = pnr[i * 3 + 2];
        float ijx = pxx - nx, ijy = pyy - ny, ijz = pzz - nz;
        float d = sqrtf(ijx * ijx + ijy * ijy + ijz * ijz);
        f4[tid][0] = d;
        f4[tid][1] = signed_angle(ijx, ijy, ijz, n1x, n1y, n1z);
        f4[tid][2] = signed_angle(-ijx, -ijy, -ijz, qx, qy, qz);
        f4[tid][3] = signed_angle(n1x, n1y, n1z, qx, qy, qz);
    }
    __syncthreads();

    // ---- glob[d] = max_k (f4[k] . W[:,d]) + b[d] ----
    {
        int d = tid;
        float w0 = W[d], w1 = W[D_MODEL + d], w2 = W[2 * D_MODEL + d], w3 = W[3 * D_MODEL + d];
        float mx = -INFINITY;
        #pragma unroll 5
        for (int k = 0; k < K_NN; ++k) {
            float v = f4[k][0] * w0 + f4[k][1] * w1 + f4[k][2] * w2 + f4[k][3] * w3;
            mx = fmaxf(mx, v);
        }
        out[(size_t)bm * D_MODEL + d] = mx + bias[d];
    }
}

extern "C" void kernel_launch(void* const* d_in, const int* in_sizes, int n_in,
                              void* d_out, int out_size, void* d_ws, size_t ws_size,
                              hipStream_t stream) {
    const float* points = (const float*)d_in[0];
    const float* nodes  = (const float*)d_in[1];
    const float* pn     = (const float*)d_in[2];
    const float* nn     = (const float*)d_in[3];
    const float* W      = (const float*)d_in[4];
    const float* bias   = (const float*)d_in[5];
    float* out = (float*)d_out;

    // ws layout: tws f32[4096] @0 ; gcount i32[4096] @16K ; cand u16[4096*768] @32K
    char* ws = (char*)d_ws;
    float* tws = (float*)ws;
    int* gcount = (int*)(ws + 16384);
    unsigned short* cand = (unsigned short*)(ws + 32768);

    ka_thresh<<<dim3(NNODE), dim3(256), 0, stream>>>(points, nodes, tws, gcount, out);
    kb_scan<<<dim3(NNODE / TN, NCHUNK), dim3(256), 0, stream>>>(points, nodes, tws, gcount, cand);
    kc_select<<<dim3(NNODE), dim3(256), 0, stream>>>(points, nodes, pn, nn, W, bias,
                                                     tws, gcount, cand, out);
}

// Round 7
// 99.318 us; speedup vs baseline: 2.2229x; 1.0855x over previous
//
#include <hip/hip_runtime.h>

#define N_PTS    20000
#define M_NODES  1024
#define BATCH    4
#define NNODE    (BATCH * M_NODES)   // 4096
#define K_NN     50
#define D_MODEL  256
#define NPF      84
#define CAP      768                 // ws candidate capacity per node
#define SELWIN   96                  // refine target window upper bound
#define TN       32                  // nodes per block in kernel B
#define CHUNK    2560                // points per chunk in kernel B
#define NCHUNK   8                   // 8*2560 = 20480 >= 20000
#define PPT      10                  // points per thread (CHUNK/256)
#define NSMP     2048                // samples for threshold
#define WLO      26                  // sample-count window (of 2048 samples)
#define WHI      50

__device__ __forceinline__ float signed_angle(float ax, float ay, float az,
                                              float bx, float by, float bz) {
    float cx = ay * bz - az * by;
    float cy = az * bx - ax * bz;
    float cz = ax * by - ay * bx;
    float s = sqrtf(cx * cx + cy * cy + cz * cz);
    float c = ax * bx + ay * by + az * bz;
    float a = atan2f(s, c);
    return (c < 0.0f) ? -a : a;
}

// ===== Kernel A: wave-per-node threshold from LDS-staged samples + pos_emb =====
__global__ __launch_bounds__(256) void ka_thresh(
    const float* __restrict__ points, const float* __restrict__ nodes,
    float* __restrict__ tws, int* __restrict__ gcount, float* __restrict__ out)
{
    __shared__ float s3[NSMP * 3];       // 24 KB staged sample points
    const int tid  = threadIdx.x;
    const int w    = tid >> 6;           // wave 0..3
    const int lane = tid & 63;
    const int bm   = blockIdx.x * 4 + w; // node handled by this wave
    const int b    = bm >> 10;
    const float* pts = points + (size_t)b * N_PTS * 3;

    // stage first 2048 points of this batch (blocks never straddle batches)
    {
        const float4* src = (const float4*)pts;
        float4* dst = (float4*)s3;
        #pragma unroll
        for (int k = 0; k < 6; ++k)
            dst[tid + 256 * k] = src[tid + 256 * k];
    }
    __syncthreads();

    const float nx = nodes[(size_t)bm * 3 + 0];
    const float ny = nodes[(size_t)bm * 3 + 1];
    const float nz = nodes[(size_t)bm * 3 + 2];

    unsigned short keys[32];
    #pragma unroll
    for (int s = 0; s < 32; ++s) {
        int j = lane + 64 * s;
        float dx = s3[3 * j + 0] - nx;
        float dy = s3[3 * j + 1] - ny;
        float dz = s3[3 * j + 2] - nz;
        float d2 = dx * dx + dy * dy + dz * dz;
        keys[s] = (unsigned short)(__float_as_uint(d2) >> 16);
    }

    // wave-local binary search (no barriers; branches wave-uniform)
    unsigned lo = 0, hi = 0x7F81u, v = 0;
    for (int it = 0; it < 16; ++it) {
        unsigned mid = lo + ((hi - lo) >> 1);
        int c = 0;
        #pragma unroll
        for (int s = 0; s < 32; ++s) c += (int)((unsigned)keys[s] < mid);
        for (int off = 32; off; off >>= 1) c += __shfl_down(c, off);
        c = __shfl(c, 0);
        if (c >= WLO && c <= WHI) { v = mid; break; }
        if (c < WLO) lo = mid; else hi = mid;
        if (hi - lo <= 1u) break;
    }
    if (v == 0) v = hi;
    if (lane == 0) { tws[bm] = __uint_as_float(v << 16); gcount[bm] = 0; }

    // pos_emb for node bm: dims lane, lane+64, lane+128, lane+192
    #pragma unroll
    for (int r = 0; r < 4; ++r) {
        int d = lane + 64 * r;
        float pv = 0.0f;
        if (d < 3 * NPF) {
            int c2 = d / NPF, rr = d - c2 * NPF, i = rr >> 1;
            float nc = (c2 == 0) ? nx : ((c2 == 1) ? ny : nz);
            const float L2_10000 = 13.287712379549449f;
            float tinv = exp2f(-L2_10000 * (float)i / 42.0f);
            float x = nc * tinv;
            pv = (rr & 1) ? cosf(x) : sinf(x);
        }
        out[(size_t)NNODE * D_MODEL + (size_t)bm * D_MODEL + d] = pv;
    }
}

// ============ Kernel B: tiled scan, append survivors per node ============
__global__ __launch_bounds__(256) void kb_scan(
    const float* __restrict__ points, const float* __restrict__ nodes,
    const float* __restrict__ tws, int* __restrict__ gcount,
    unsigned short* __restrict__ cand)
{
    __shared__ float4 snd[TN];
    const int tile = blockIdx.x;
    const int ch   = blockIdx.y;
    const int ngb  = tile * TN;
    const int b    = ngb >> 10;
    const int tid  = threadIdx.x, lane = tid & 63;
    const float* pts = points + (size_t)b * N_PTS * 3;

    if (tid < TN) {
        int ng = ngb + tid;
        snd[tid] = make_float4(nodes[(size_t)ng * 3 + 0], nodes[(size_t)ng * 3 + 1],
                               nodes[(size_t)ng * 3 + 2], tws[ng]);
    }
    __syncthreads();

    const int base0 = ch * CHUNK;
    float px[PPT], py[PPT], pz[PPT];
    #pragma unroll
    for (int p = 0; p < PPT; ++p) {
        int j = base0 + p * 256 + tid;
        bool ok = j < N_PTS;
        int jj = ok ? j : 0;
        float vx = pts[jj * 3 + 0], vy = pts[jj * 3 + 1], vz = pts[jj * 3 + 2];
        px[p] = ok ? vx : 1e18f;
        py[p] = ok ? vy : 1e18f;
        pz[p] = ok ? vz : 1e18f;
    }

    for (int n = 0; n < TN; ++n) {
        float4 nd = snd[n];
        unsigned m = 0;
        #pragma unroll
        for (int p = 0; p < PPT; ++p) {
            float dx = px[p] - nd.x, dy = py[p] - nd.y, dz = pz[p] - nd.z;
            float d2 = dx * dx + dy * dy + dz * dz;
            m |= (d2 < nd.w) ? (1u << p) : 0u;
        }
        int cnt = __popc(m);
        int inc = cnt;
        #pragma unroll
        for (int s = 1; s < 64; s <<= 1) {
            int u = __shfl_up(inc, s);
            if (lane >= s) inc += u;
        }
        int wtot = __shfl(inc, 63);
        if (wtot) {
            int basew = 0;
            if (lane == 63) basew = atomicAdd(&gcount[ngb + n], wtot);
            basew = __shfl(basew, 63);
            int w = basew + inc - cnt;
            unsigned mm = m;
            while (mm) {
                int p = __ffs(mm) - 1; mm &= mm - 1;
                if (w < CAP)
                    cand[(size_t)(ngb + n) * CAP + w] =
                        (unsigned short)(base0 + p * 256 + tid);
                ++w;
            }
        }
    }
}

// ============ Kernel C: exact top-50 select + PPF features + projection ============
__global__ __launch_bounds__(256) void kc_select(
    const float* __restrict__ points, const float* __restrict__ nodes,
    const float* __restrict__ pnrm, const float* __restrict__ nnrm,
    const float* __restrict__ W, const float* __restrict__ bias,
    const float* __restrict__ tws, const int* __restrict__ gcount,
    const unsigned short* __restrict__ cand, float* __restrict__ out)
{
    __shared__ unsigned long long sel[CAP];
    __shared__ int red[4];
    __shared__ int selidx[K_NN];
    __shared__ float4 f4v[K_NN];
    __shared__ int s_pos;

    const int bm = blockIdx.x, b = bm >> 10, tid = threadIdx.x, lane = tid & 63;
    const float* pts = points + (size_t)b * N_PTS * 3;
    const float* pnr = pnrm   + (size_t)b * N_PTS * 3;
    const float nx  = nodes[(size_t)bm * 3 + 0];
    const float ny  = nodes[(size_t)bm * 3 + 1];
    const float nz  = nodes[(size_t)bm * 3 + 2];
    const float n1x = nnrm[(size_t)bm * 3 + 0];
    const float n1y = nnrm[(size_t)bm * 3 + 1];
    const float n1z = nnrm[(size_t)bm * 3 + 2];

    auto d2bits = [&](int i) -> unsigned int {
        float dx = pts[i * 3 + 0] - nx;
        float dy = pts[i * 3 + 1] - ny;
        float dz = pts[i * 3 + 2] - nz;
        return __float_as_uint(dx * dx + dy * dy + dz * dz);
    };
    auto blockSum = [&](int c) -> int {
        for (int off = 32; off > 0; off >>= 1) c += __shfl_down(c, off);
        if (lane == 0) red[tid >> 6] = c;
        __syncthreads();
        int total = red[0] + red[1] + red[2] + red[3];
        __syncthreads();
        return total;
    };
    auto countb = [&](unsigned tb) -> int {     // global rescan (slow path only)
        float tf = __uint_as_float(tb);
        int c = 0;
        for (int i = tid; i < N_PTS; i += 256) {
            float dx = pts[i * 3 + 0] - nx;
            float dy = pts[i * 3 + 1] - ny;
            float dz = pts[i * 3 + 2] - nz;
            c += (int)(dx * dx + dy * dy + dz * dz < tf);
        }
        return blockSum(c);
    };

    if (tid < K_NN) selidx[tid] = 0;   // defense vs pathological ties

    const unsigned long long INVALID = ~0ull;
    int cnt = gcount[bm];              // EXACT survivor count
    int nsel = 0;

    if (cnt >= K_NN && cnt <= CAP) {
        // ---- fast path: keys in registers ----
        const unsigned short* cp = cand + (size_t)bm * CAP;
        unsigned long long k0 = INVALID, k1 = INVALID, k2 = INVALID;
        if (tid < cnt) {
            int i = (int)cp[tid];
            k0 = ((unsigned long long)d2bits(i) << 32) | (unsigned int)i;
        }
        if (tid + 256 < cnt) {
            int i = (int)cp[tid + 256];
            k1 = ((unsigned long long)d2bits(i) << 32) | (unsigned int)i;
        }
        if (tid + 512 < cnt) {
            int i = (int)cp[tid + 512];
            k2 = ((unsigned long long)d2bits(i) << 32) | (unsigned int)i;
        }

        // refine cut so that #selected in [K_NN, SELWIN]; all keys < tws bits
        unsigned long long tcut = INVALID;
        bool conv = (cnt <= SELWIN);            // take-all if already small
        if (!conv) {
            unsigned lo = 0, hi = __float_as_uint(tws[bm]);  // count(<hi)=cnt>SELWIN
            for (int it = 0; it < 32 && !conv; ++it) {
                unsigned mid = lo + ((hi - lo) >> 1);
                unsigned long long tm = (unsigned long long)mid << 32;
                int c = (int)(k0 < tm) + (int)(k1 < tm) + (int)(k2 < tm);
                c = blockSum(c);
                if (c >= K_NN && c <= SELWIN) { tcut = tm; conv = true; }
                else if (c < K_NN) lo = mid;
                else hi = mid;
                if (hi - lo <= 1u) break;
            }
            // !conv (pathological ties): tcut stays INVALID -> select all, full rank
        }

        __syncthreads();
        if (tid == 0) s_pos = 0;
        __syncthreads();
        unsigned long long ks[3] = {k0, k1, k2};
        #pragma unroll
        for (int r = 0; r < 3; ++r) {
            bool p = ks[r] < tcut;
            unsigned long long mask = __ballot(p);
            if (mask) {
                int basew = 0;
                if (lane == 0) basew = atomicAdd(&s_pos, (int)__popcll(mask));
                basew = __shfl(basew, 0);
                if (p) {
                    int q = basew + (int)__popcll(mask & ((1ull << lane) - 1ull));
                    sel[q] = ks[r];   // q < cnt <= CAP always
                }
            }
        }
        __syncthreads();
        nsel = s_pos;
    } else {
        // ---- slow path (expected ~never): global threshold repair + compact ----
        unsigned tb = __float_as_uint(tws[bm]);
        unsigned lo = 0, hi = 0x7F000000u, good = 0;
        bool haveLo = false, haveHi = false;
        if (cnt < K_NN) { lo = tb; haveLo = true; }
        else            { hi = tb; haveHi = true; }
        unsigned cur = tb;
        for (int a = 0; a < 40 && !good; ++a) {
            if (haveLo && !haveHi) {
                cur = (cur < 0x7E800000u) ? cur + 0x00800000u : 0x7F000000u;
            } else if (haveHi && !haveLo) {
                cur = (cur >= 0x00800000u) ? cur - 0x00800000u : (cur >> 1);
            } else {
                cur = lo + ((hi - lo) >> 1);
                if (hi - lo <= 1u) { good = hi; break; }
            }
            int c = countb(cur);
            if (c >= K_NN && c <= CAP) good = cur;
            else if (c < K_NN) { lo = cur; haveLo = true; }
            else               { hi = cur; haveHi = true; }
        }
        if (!good) good = haveHi ? hi : 0x7F000000u;
        __syncthreads();
        if (tid == 0) s_pos = 0;
        __syncthreads();
        float tf = __uint_as_float(good);
        for (int i = tid; i < N_PTS; i += 256) {
            unsigned kb = d2bits(i);
            bool pred = __uint_as_float(kb) < tf;
            unsigned long long mask = __ballot(pred);
            if (mask) {
                int basew = 0;
                if (lane == 0) basew = atomicAdd(&s_pos, (int)__popcll(mask));
                basew = __shfl(basew, 0);
                if (pred) {
                    int q = basew + (int)__popcll(mask & ((1ull << lane) - 1ull));
                    if (q < CAP)
                        sel[q] = ((unsigned long long)kb << 32) | (unsigned int)i;
                }
            }
        }
        __syncthreads();
        nsel = s_pos < CAP ? s_pos : CAP;
    }

    // ---- exact rank selection of the 50 nearest (ties -> low idx) ----
    for (int s = tid; s < nsel; s += 256) {
        unsigned long long mykey = sel[s];
        int rank = 0;
        #pragma unroll 4
        for (int j = 0; j < nsel; ++j) rank += (int)(sel[j] < mykey);
        if (rank < K_NN) selidx[rank] = (int)(mykey & 0xFFFFFFFFull);
    }
    __syncthreads();

    // ---- PPF features ----
    if (tid < K_NN) {
        int i = selidx[tid];
        float pxx = pts[i * 3 + 0], pyy = pts[i * 3 + 1], pzz = pts[i * 3 + 2];
        float qx = pnr[i * 3 + 0], qy = pnr[i * 3 + 1], qz = pnr[i * 3 + 2];
        float ijx = pxx - nx, ijy = pyy - ny, ijz = pzz - nz;
        float d = sqrtf(ijx * ijx + ijy * ijy + ijz * ijz);
        f4v[tid] = make_float4(d,
                               signed_angle(ijx, ijy, ijz, n1x, n1y, n1z),
                               signed_angle(-ijx, -ijy, -ijz, qx, qy, qz),
                               signed_angle(n1x, n1y, n1z, qx, qy, qz));
    }
    __syncthreads();

    // ---- glob[d] = max_k (f4[k] . W[:,d]) + b[d] ----
    {
        int d = tid;
        float w0 = W[d], w1 = W[D_MODEL + d], w2 = W[2 * D_MODEL + d], w3 = W[3 * D_MODEL + d];
        float mx = -INFINITY;
        #pragma unroll 5
        for (int k = 0; k < K_NN; ++k) {
            float4 f = f4v[k];
            float v = f.x * w0 + f.y * w1 + f.z * w2 + f.w * w3;
            mx = fmaxf(mx, v);
        }
        out[(size_t)bm * D_MODEL + d] = mx + bias[d];
    }
}

extern "C" void kernel_launch(void* const* d_in, const int* in_sizes, int n_in,
                              void* d_out, int out_size, void* d_ws, size_t ws_size,
                              hipStream_t stream) {
    const float* points = (const float*)d_in[0];
    const float* nodes  = (const float*)d_in[1];
    const float* pn     = (const float*)d_in[2];
    const float* nn     = (const float*)d_in[3];
    const float* W      = (const float*)d_in[4];
    const float* bias   = (const float*)d_in[5];
    float* out = (float*)d_out;

    // ws layout: tws f32[4096] @0 ; gcount i32[4096] @16K ; cand u16[4096*768] @32K
    char* ws = (char*)d_ws;
    float* tws = (float*)ws;
    int* gcount = (int*)(ws + 16384);
    unsigned short* cand = (unsigned short*)(ws + 32768);

    ka_thresh<<<dim3(NNODE / 4), dim3(256), 0, stream>>>(points, nodes, tws, gcount, out);
    kb_scan<<<dim3(NNODE / TN, NCHUNK), dim3(256), 0, stream>>>(points, nodes, tws, gcount, cand);
    kc_select<<<dim3(NNODE), dim3(256), 0, stream>>>(points, nodes, pn, nn, W, bias,
                                                     tws, gcount, cand, out);
}

// Round 8
// 98.708 us; speedup vs baseline: 2.2367x; 1.0062x over previous
//
#include <hip/hip_runtime.h>

#define N_PTS    20000
#define M_NODES  1024
#define BATCH    4
#define NNODE    (BATCH * M_NODES)   // 4096
#define K_NN     50
#define D_MODEL  256
#define NPF      84
#define CAP      768                 // ws candidate capacity per node
#define SELWIN   96                  // refine target window upper bound
#define NSMP     2048                // samples for threshold
#define WLO      26                  // sample-count window (of 2048 samples)
#define WHI      50
// kernel B staging
#define KB_CHUNK      2560           // points per staged chunk
#define KB_NCHUNK     8              // 8*2560 = 20480 >= 20000
#define KB_F4_CHUNK   1920           // 2560*3/4 float4 per chunk
#define KB_F4_TOTAL   15000          // 20000*3/4 float4 per batch

__device__ __forceinline__ float signed_angle(float ax, float ay, float az,
                                              float bx, float by, float bz) {
    float cx = ay * bz - az * by;
    float cy = az * bx - ax * bz;
    float cz = ax * by - ay * bx;
    float s = sqrtf(cx * cx + cy * cy + cz * cz);
    float c = ax * bx + ay * by + az * bz;
    float a = atan2f(s, c);
    return (c < 0.0f) ? -a : a;
}

// ===== Kernel A: wave-per-node threshold from LDS-staged samples + pos_emb =====
__global__ __launch_bounds__(256) void ka_thresh(
    const float* __restrict__ points, const float* __restrict__ nodes,
    float* __restrict__ tws, float* __restrict__ out)
{
    __shared__ float s3[NSMP * 3];       // 24 KB staged sample points
    const int tid  = threadIdx.x;
    const int w    = tid >> 6;
    const int lane = tid & 63;
    const int bm   = blockIdx.x * 4 + w;
    const int b    = bm >> 10;
    const float* pts = points + (size_t)b * N_PTS * 3;

    {
        const float4* src = (const float4*)pts;
        float4* dst = (float4*)s3;
        #pragma unroll
        for (int k = 0; k < 6; ++k)
            dst[tid + 256 * k] = src[tid + 256 * k];
    }
    __syncthreads();

    const float nx = nodes[(size_t)bm * 3 + 0];
    const float ny = nodes[(size_t)bm * 3 + 1];
    const float nz = nodes[(size_t)bm * 3 + 2];

    unsigned short keys[32];
    #pragma unroll
    for (int s = 0; s < 32; ++s) {
        int j = lane + 64 * s;
        float dx = s3[3 * j + 0] - nx;
        float dy = s3[3 * j + 1] - ny;
        float dz = s3[3 * j + 2] - nz;
        float d2 = dx * dx + dy * dy + dz * dz;
        keys[s] = (unsigned short)(__float_as_uint(d2) >> 16);
    }

    unsigned lo = 0, hi = 0x7F81u, v = 0;
    for (int it = 0; it < 16; ++it) {
        unsigned mid = lo + ((hi - lo) >> 1);
        int c = 0;
        #pragma unroll
        for (int s = 0; s < 32; ++s) c += (int)((unsigned)keys[s] < mid);
        for (int off = 32; off; off >>= 1) c += __shfl_down(c, off);
        c = __shfl(c, 0);
        if (c >= WLO && c <= WHI) { v = mid; break; }
        if (c < WLO) lo = mid; else hi = mid;
        if (hi - lo <= 1u) break;
    }
    if (v == 0) v = hi;
    if (lane == 0) tws[bm] = __uint_as_float(v << 16);

    #pragma unroll
    for (int r = 0; r < 4; ++r) {
        int d = lane + 64 * r;
        float pv = 0.0f;
        if (d < 3 * NPF) {
            int c2 = d / NPF, rr = d - c2 * NPF, i = rr >> 1;
            float nc = (c2 == 0) ? nx : ((c2 == 1) ? ny : nz);
            const float L2_10000 = 13.287712379549449f;
            float tinv = exp2f(-L2_10000 * (float)i / 42.0f);
            float x = nc * tinv;
            pv = (rr & 1) ? cosf(x) : sinf(x);
        }
        out[(size_t)NNODE * D_MODEL + (size_t)bm * D_MODEL + d] = pv;
    }
}

// ===== Kernel B: wave-per-node scan over LDS-staged chunks; no atomics =====
__global__ __launch_bounds__(256) void kb_scan(
    const float* __restrict__ points, const float* __restrict__ nodes,
    const float* __restrict__ tws, int* __restrict__ gcount,
    unsigned short* __restrict__ cand)
{
    __shared__ float4 spts4[KB_F4_CHUNK];    // 30 KB
    const int tid  = threadIdx.x;
    const int wv   = tid >> 6;
    const int lane = tid & 63;
    const int bm   = blockIdx.x * 4 + wv;
    const int b    = bm >> 10;
    const float4* src = (const float4*)points + (size_t)b * KB_F4_TOTAL;

    const float nx = nodes[(size_t)bm * 3 + 0];
    const float ny = nodes[(size_t)bm * 3 + 1];
    const float nz = nodes[(size_t)bm * 3 + 2];
    const float t  = tws[bm];
    unsigned short* cp = cand + (size_t)bm * CAP;

    int running = 0;
    for (int c = 0; c < KB_NCHUNK; ++c) {
        __syncthreads();                 // protect LDS reuse across chunks
        #pragma unroll
        for (int k = 0; k < 8; ++k) {
            int slot = k * 256 + tid;
            if (slot < KB_F4_CHUNK) {
                int g = c * KB_F4_CHUNK + slot;
                spts4[slot] = (g < KB_F4_TOTAL) ? src[g]
                              : make_float4(1e18f, 1e18f, 1e18f, 1e18f);
            }
        }
        __syncthreads();
        const float* sp = (const float*)spts4;
        #pragma unroll 4
        for (int it = 0; it < KB_CHUNK / 64; ++it) {
            int j = it * 64 + lane;
            float dx = sp[3 * j + 0] - nx;
            float dy = sp[3 * j + 1] - ny;
            float dz = sp[3 * j + 2] - nz;
            float d2 = dx * dx + dy * dy + dz * dz;
            bool pred = d2 < t;
            unsigned long long mask = __ballot(pred);
            if (pred) {
                int p = running + (int)__popcll(mask & ((1ull << lane) - 1ull));
                if (p < CAP) cp[p] = (unsigned short)(c * KB_CHUNK + j);
            }
            running += (int)__popcll(mask);
        }
    }
    if (lane == 0) gcount[bm] = running;
}

// ===== Kernel C: wave-per-node exact top-50 + PPF features + projection =====
__global__ __launch_bounds__(256) void kc_select(
    const float* __restrict__ points, const float* __restrict__ nodes,
    const float* __restrict__ pnrm, const float* __restrict__ nnrm,
    const float* __restrict__ W, const float* __restrict__ bias,
    const float* __restrict__ tws, const int* __restrict__ gcount,
    const unsigned short* __restrict__ cand, float* __restrict__ out)
{
    __shared__ unsigned long long skeys[4][CAP];   // 24.6 KB
    __shared__ float4 f4v[4][K_NN];                // 3.2 KB
    __shared__ unsigned short selidx[4][K_NN];     // 0.4 KB

    const int tid  = threadIdx.x;
    const int wv   = tid >> 6;
    const int lane = tid & 63;
    const int bm   = blockIdx.x * 4 + wv;
    const int b    = bm >> 10;
    const float* pts = points + (size_t)b * N_PTS * 3;
    const float* pnr = pnrm   + (size_t)b * N_PTS * 3;
    const float nx  = nodes[(size_t)bm * 3 + 0];
    const float ny  = nodes[(size_t)bm * 3 + 1];
    const float nz  = nodes[(size_t)bm * 3 + 2];
    const float n1x = nnrm[(size_t)bm * 3 + 0];
    const float n1y = nnrm[(size_t)bm * 3 + 1];
    const float n1z = nnrm[(size_t)bm * 3 + 2];

    auto d2bits = [&](int i) -> unsigned int {
        float dx = pts[i * 3 + 0] - nx;
        float dy = pts[i * 3 + 1] - ny;
        float dz = pts[i * 3 + 2] - nz;
        return __float_as_uint(dx * dx + dy * dy + dz * dz);
    };

    if (lane < K_NN) selidx[wv][lane] = 0;   // defense vs pathological ties

    const unsigned long long INVALID = ~0ull;
    int cnt = gcount[bm];
    int nsel = 0;

    if (cnt >= K_NN && cnt <= CAP) {
        // ---- fast path: candidate keys in registers, ballot-count refine ----
        const unsigned short* cp = cand + (size_t)bm * CAP;
        unsigned long long key[12];
        #pragma unroll
        for (int r = 0; r < 12; ++r) {
            int s = r * 64 + lane;
            key[r] = INVALID;
            if (s < cnt) {
                int i = (int)cp[s];
                key[r] = ((unsigned long long)d2bits(i) << 32) | (unsigned int)i;
            }
        }

        unsigned long long tcut = INVALID;   // take-all if cnt small or no converge
        bool conv = (cnt <= SELWIN);
        if (!conv) {
            unsigned lo = 0, hi = __float_as_uint(tws[bm]);
            for (int it = 0; it < 32 && !conv; ++it) {
                unsigned mid = lo + ((hi - lo) >> 1);
                unsigned long long tm = (unsigned long long)mid << 32;
                int c = 0;
                #pragma unroll
                for (int r = 0; r < 12; ++r)
                    c += (int)__popcll(__ballot(key[r] < tm));
                if (c >= K_NN && c <= SELWIN) { tcut = tm; conv = true; }
                else if (c < K_NN) lo = mid;
                else hi = mid;
                if (hi - lo <= 1u) break;
            }
        }

        int run = 0;
        #pragma unroll
        for (int r = 0; r < 12; ++r) {
            bool p = key[r] < tcut;
            unsigned long long mask = __ballot(p);
            if (p) {
                int q = run + (int)__popcll(mask & ((1ull << lane) - 1ull));
                skeys[wv][q] = key[r];       // q < cnt <= CAP always
            }
            run += (int)__popcll(mask);
        }
        nsel = run;
    } else {
        // ---- slow path (expected ~never): wave-local global repair ----
        unsigned tb = __float_as_uint(tws[bm]);
        unsigned lo = 0, hi = 0x7F000000u, good = 0;
        bool haveLo = false, haveHi = false;
        if (cnt < K_NN) { lo = tb; haveLo = true; }
        else            { hi = tb; haveHi = true; }
        unsigned cur = tb;
        for (int a = 0; a < 40 && !good; ++a) {
            if (haveLo && !haveHi) {
                cur = (cur < 0x7E800000u) ? cur + 0x00800000u : 0x7F000000u;
            } else if (haveHi && !haveLo) {
                cur = (cur >= 0x00800000u) ? cur - 0x00800000u : (cur >> 1);
            } else {
                cur = lo + ((hi - lo) >> 1);
                if (hi - lo <= 1u) { good = hi; break; }
            }
            float tf = __uint_as_float(cur);
            int c = 0;
            for (int i0 = lane; i0 < N_PTS; i0 += 64) {
                float dx = pts[i0 * 3 + 0] - nx;
                float dy = pts[i0 * 3 + 1] - ny;
                float dz = pts[i0 * 3 + 2] - nz;
                c += (int)(dx * dx + dy * dy + dz * dz < tf);
            }
            for (int off = 32; off; off >>= 1) c += __shfl_down(c, off);
            c = __shfl(c, 0);
            if (c >= K_NN && c <= CAP) good = cur;
            else if (c < K_NN) { lo = cur; haveLo = true; }
            else               { hi = cur; haveHi = true; }
        }
        if (!good) good = haveHi ? hi : 0x7F000000u;
        int run = 0;
        for (int base = 0; base < N_PTS; base += 64) {
            int i0 = base + lane;
            bool pred = false;
            unsigned kb2 = 0;
            if (i0 < N_PTS) { kb2 = d2bits(i0); pred = kb2 < good; }
            unsigned long long mask = __ballot(pred);
            if (pred) {
                int q = run + (int)__popcll(mask & ((1ull << lane) - 1ull));
                if (q < CAP)
                    skeys[wv][q] = ((unsigned long long)kb2 << 32) | (unsigned int)i0;
            }
            run += (int)__popcll(mask);
        }
        nsel = run < CAP ? run : CAP;
    }
    __syncthreads();

    // ---- exact rank selection of the 50 nearest (ties -> low idx) ----
    for (int s = lane; s < nsel; s += 64) {
        unsigned long long mk = skeys[wv][s];
        int rank = 0;
        for (int j = 0; j < nsel; ++j) rank += (int)(skeys[wv][j] < mk);
        if (rank < K_NN) selidx[wv][rank] = (unsigned short)mk;  // idx < 65536
    }
    __syncthreads();

    // ---- PPF features (one neighbor per lane) ----
    if (lane < K_NN) {
        int i = (int)selidx[wv][lane];
        float pxx = pts[i * 3 + 0], pyy = pts[i * 3 + 1], pzz = pts[i * 3 + 2];
        float qx = pnr[i * 3 + 0], qy = pnr[i * 3 + 1], qz = pnr[i * 3 + 2];
        float ijx = pxx - nx, ijy = pyy - ny, ijz = pzz - nz;
        float d = sqrtf(ijx * ijx + ijy * ijy + ijz * ijz);
        f4v[wv][lane] = make_float4(d,
                                    signed_angle(ijx, ijy, ijz, n1x, n1y, n1z),
                                    signed_angle(-ijx, -ijy, -ijz, qx, qy, qz),
                                    signed_angle(n1x, n1y, n1z, qx, qy, qz));
    }
    __syncthreads();

    // ---- glob[d] = max_k (f4[k] . W[:,d]) + b[d] ; 4 dims per lane ----
    {
        float w0[4], w1[4], w2[4], w3[4], bb[4], mx[4];
        #pragma unroll
        for (int q = 0; q < 4; ++q) {
            int d = lane + 64 * q;
            w0[q] = W[d]; w1[q] = W[D_MODEL + d];
            w2[q] = W[2 * D_MODEL + d]; w3[q] = W[3 * D_MODEL + d];
            bb[q] = bias[d]; mx[q] = -INFINITY;
        }
        #pragma unroll 5
        for (int k = 0; k < K_NN; ++k) {
            float4 f = f4v[wv][k];
            #pragma unroll
            for (int q = 0; q < 4; ++q)
                mx[q] = fmaxf(mx[q], f.x * w0[q] + f.y * w1[q] + f.z * w2[q] + f.w * w3[q]);
        }
        #pragma unroll
        for (int q = 0; q < 4; ++q)
            out[(size_t)bm * D_MODEL + lane + 64 * q] = mx[q] + bb[q];
    }
}

extern "C" void kernel_launch(void* const* d_in, const int* in_sizes, int n_in,
                              void* d_out, int out_size, void* d_ws, size_t ws_size,
                              hipStream_t stream) {
    const float* points = (const float*)d_in[0];
    const float* nodes  = (const float*)d_in[1];
    const float* pn     = (const float*)d_in[2];
    const float* nn     = (const float*)d_in[3];
    const float* W      = (const float*)d_in[4];
    const float* bias   = (const float*)d_in[5];
    float* out = (float*)d_out;

    // ws layout: tws f32[4096] @0 ; gcount i32[4096] @16K ; cand u16[4096*768] @32K
    char* ws = (char*)d_ws;
    float* tws = (float*)ws;
    int* gcount = (int*)(ws + 16384);
    unsigned short* cand = (unsigned short*)(ws + 32768);

    ka_thresh<<<dim3(NNODE / 4), dim3(256), 0, stream>>>(points, nodes, tws, out);
    kb_scan<<<dim3(NNODE / 4), dim3(256), 0, stream>>>(points, nodes, tws, gcount, cand);
    kc_select<<<dim3(NNODE / 4), dim3(256), 0, stream>>>(points, nodes, pn, nn, W, bias,
                                                         tws, gcount, cand, out);
}

// Round 9
// 74.200 us; speedup vs baseline: 2.9754x; 1.3303x over previous
//
#include <hip/hip_runtime.h>

#define N_PTS    20000
#define M_NODES  1024
#define BATCH    4
#define NNODE    (BATCH * M_NODES)   // 4096
#define K_NN     50
#define D_MODEL  256
#define NPF      84
#define CAP      768                 // ws candidate capacity per node
#define SELWIN   96                  // refine target window upper bound
#define NSMP     2048                // samples for threshold
#define WLO      26                  // sample-count window (of 2048 samples)
#define WHI      50
// kernel B tiling
#define TN        32                 // nodes per block
#define KB_PPT    10                 // points per thread
#define KB_CHUNK  2560               // 256*10 points per chunk-block
#define KB_NCHUNK 8                  // 8*2560 = 20480 >= 20000
#define LOCAL_CAP 128                // per-node per-chunk survivor buffer
#define OVF_FLAG  (1 << 20)

__device__ __forceinline__ float signed_angle(float ax, float ay, float az,
                                              float bx, float by, float bz) {
    float cx = ay * bz - az * by;
    float cy = az * bx - ax * bz;
    float cz = ax * by - ay * bx;
    float s = sqrtf(cx * cx + cy * cy + cz * cz);
    float c = ax * bx + ay * by + az * bz;
    float a = atan2f(s, c);
    return (c < 0.0f) ? -a : a;
}

// ===== Kernel A: wave-per-node threshold from LDS-staged samples + pos_emb =====
__global__ __launch_bounds__(256) void ka_thresh(
    const float* __restrict__ points, const float* __restrict__ nodes,
    float* __restrict__ tws, int* __restrict__ gcount, float* __restrict__ out)
{
    __shared__ float s3[NSMP * 3];       // 24 KB staged sample points
    const int tid  = threadIdx.x;
    const int w    = tid >> 6;
    const int lane = tid & 63;
    const int bm   = blockIdx.x * 4 + w;
    const int b    = bm >> 10;
    const float* pts = points + (size_t)b * N_PTS * 3;

    {
        const float4* src = (const float4*)pts;
        float4* dst = (float4*)s3;
        #pragma unroll
        for (int k = 0; k < 6; ++k)
            dst[tid + 256 * k] = src[tid + 256 * k];
    }
    __syncthreads();

    const float nx = nodes[(size_t)bm * 3 + 0];
    const float ny = nodes[(size_t)bm * 3 + 1];
    const float nz = nodes[(size_t)bm * 3 + 2];

    unsigned short keys[32];
    #pragma unroll
    for (int s = 0; s < 32; ++s) {
        int j = lane + 64 * s;
        float dx = s3[3 * j + 0] - nx;
        float dy = s3[3 * j + 1] - ny;
        float dz = s3[3 * j + 2] - nz;
        float d2 = dx * dx + dy * dy + dz * dz;
        keys[s] = (unsigned short)(__float_as_uint(d2) >> 16);
    }

    unsigned lo = 0, hi = 0x7F81u, v = 0;
    for (int it = 0; it < 16; ++it) {
        unsigned mid = lo + ((hi - lo) >> 1);
        int c = 0;
        #pragma unroll
        for (int s = 0; s < 32; ++s) c += (int)((unsigned)keys[s] < mid);
        for (int off = 32; off; off >>= 1) c += __shfl_down(c, off);
        c = __shfl(c, 0);
        if (c >= WLO && c <= WHI) { v = mid; break; }
        if (c < WLO) lo = mid; else hi = mid;
        if (hi - lo <= 1u) break;
    }
    if (v == 0) v = hi;
    if (lane == 0) { tws[bm] = __uint_as_float(v << 16); gcount[bm] = 0; }

    #pragma unroll
    for (int r = 0; r < 4; ++r) {
        int d = lane + 64 * r;
        float pv = 0.0f;
        if (d < 3 * NPF) {
            int c2 = d / NPF, rr = d - c2 * NPF, i = rr >> 1;
            float nc = (c2 == 0) ? nx : ((c2 == 1) ? ny : nz);
            const float L2_10000 = 13.287712379549449f;
            float tinv = exp2f(-L2_10000 * (float)i / 42.0f);
            float x = nc * tinv;
            pv = (rr & 1) ? cosf(x) : sinf(x);
        }
        out[(size_t)NNODE * D_MODEL + (size_t)bm * D_MODEL + d] = pv;
    }
}

// ===== Kernel B: node-tiled scan, reg-held points, LDS survivor buffers =====
__global__ __launch_bounds__(256) void kb_scan(
    const float* __restrict__ points, const float* __restrict__ nodes,
    const float* __restrict__ tws, int* __restrict__ gcount,
    unsigned short* __restrict__ cand)
{
    __shared__ float4 snd[TN];
    __shared__ unsigned short sbuf[TN][LOCAL_CAP];   // 8 KB
    __shared__ int scnt[TN];
    __shared__ int sbase[TN];

    const int tile = blockIdx.x;          // 0..127
    const int ch   = blockIdx.y;          // 0..7
    const int ngb  = tile * TN;
    const int b    = ngb >> 10;
    const int tid  = threadIdx.x;
    const float* pts = points + (size_t)b * N_PTS * 3;

    if (tid < TN) {
        int ng = ngb + tid;
        snd[tid] = make_float4(nodes[(size_t)ng * 3 + 0], nodes[(size_t)ng * 3 + 1],
                               nodes[(size_t)ng * 3 + 2], tws[ng]);
        scnt[tid] = 0;
    }
    __syncthreads();

    const int base0 = ch * KB_CHUNK;
    float px[KB_PPT], py[KB_PPT], pz[KB_PPT];
    #pragma unroll
    for (int p = 0; p < KB_PPT; ++p) {
        int j = base0 + p * 256 + tid;
        bool ok = j < N_PTS;
        int jj = ok ? j : 0;
        float vx = pts[jj * 3 + 0], vy = pts[jj * 3 + 1], vz = pts[jj * 3 + 2];
        px[p] = ok ? vx : 1e18f;
        py[p] = ok ? vy : 1e18f;
        pz[p] = ok ? vz : 1e18f;
    }

    for (int n = 0; n < TN; ++n) {
        float4 nd = snd[n];
        unsigned m = 0;
        #pragma unroll
        for (int p = 0; p < KB_PPT; ++p) {
            float dx = px[p] - nd.x, dy = py[p] - nd.y, dz = pz[p] - nd.z;
            float d2 = dx * dx + dy * dy + dz * dz;
            m |= (d2 < nd.w) ? (1u << p) : 0u;
        }
        if (m) {                      // taken ~14% of the time
            do {
                int p = __ffs(m) - 1; m &= m - 1;
                int q = atomicAdd(&scnt[n], 1);
                if (q < LOCAL_CAP)
                    sbuf[n][q] = (unsigned short)(base0 + p * 256 + tid);
            } while (m);
        }
    }
    __syncthreads();

    if (tid < TN) {
        int c = scnt[tid];
        int flag = (c > LOCAL_CAP) ? OVF_FLAG : 0;   // forces kc slow path
        sbase[tid] = atomicAdd(&gcount[ngb + tid], c + flag);
        scnt[tid] = (c < LOCAL_CAP) ? c : LOCAL_CAP;
    }
    __syncthreads();

    // copy out: wave wv handles its 8 nodes
    const int wv = tid >> 6, lane = tid & 63;
    #pragma unroll
    for (int nn = 0; nn < TN / 4; ++nn) {
        int n = wv * (TN / 4) + nn;
        int c = scnt[n], gb = sbase[n];
        for (int s = lane; s < c; s += 64) {
            int pos = gb + s;
            if (pos < CAP)
                cand[(size_t)(ngb + n) * CAP + pos] = sbuf[n][s];
        }
    }
}

// ===== Kernel C: wave-per-node exact top-50 + PPF features + projection =====
__global__ __launch_bounds__(256) void kc_select(
    const float* __restrict__ points, const float* __restrict__ nodes,
    const float* __restrict__ pnrm, const float* __restrict__ nnrm,
    const float* __restrict__ W, const float* __restrict__ bias,
    const float* __restrict__ tws, const int* __restrict__ gcount,
    const unsigned short* __restrict__ cand, float* __restrict__ out)
{
    __shared__ unsigned long long skeys[4][CAP];   // 24.6 KB
    __shared__ float4 f4v[4][K_NN];
    __shared__ unsigned short selidx[4][K_NN];

    const int tid  = threadIdx.x;
    const int wv   = tid >> 6;
    const int lane = tid & 63;
    const int bm   = blockIdx.x * 4 + wv;
    const int b    = bm >> 10;
    const float* pts = points + (size_t)b * N_PTS * 3;
    const float* pnr = pnrm   + (size_t)b * N_PTS * 3;
    const float nx  = nodes[(size_t)bm * 3 + 0];
    const float ny  = nodes[(size_t)bm * 3 + 1];
    const float nz  = nodes[(size_t)bm * 3 + 2];
    const float n1x = nnrm[(size_t)bm * 3 + 0];
    const float n1y = nnrm[(size_t)bm * 3 + 1];
    const float n1z = nnrm[(size_t)bm * 3 + 2];

    auto d2bits = [&](int i) -> unsigned int {
        float dx = pts[i * 3 + 0] - nx;
        float dy = pts[i * 3 + 1] - ny;
        float dz = pts[i * 3 + 2] - nz;
        return __float_as_uint(dx * dx + dy * dy + dz * dz);
    };

    if (lane < K_NN) selidx[wv][lane] = 0;   // defense vs pathological ties

    const unsigned long long INVALID = ~0ull;
    int cnt = gcount[bm];
    int nsel = 0;

    if (cnt >= K_NN && cnt <= CAP) {
        // ---- fast path: candidate keys in registers, ballot-count refine ----
        const unsigned short* cp = cand + (size_t)bm * CAP;
        unsigned long long key[12];
        #pragma unroll
        for (int r = 0; r < 12; ++r) {
            int s = r * 64 + lane;
            key[r] = INVALID;
            if (s < cnt) {
                int i = (int)cp[s];
                key[r] = ((unsigned long long)d2bits(i) << 32) | (unsigned int)i;
            }
        }

        unsigned long long tcut = INVALID;   // take-all if cnt small or no converge
        bool conv = (cnt <= SELWIN);
        if (!conv) {
            unsigned lo = 0, hi = __float_as_uint(tws[bm]);
            for (int it = 0; it < 32 && !conv; ++it) {
                unsigned mid = lo + ((hi - lo) >> 1);
                unsigned long long tm = (unsigned long long)mid << 32;
                int c = 0;
                #pragma unroll
                for (int r = 0; r < 12; ++r)
                    c += (int)__popcll(__ballot(key[r] < tm));
                if (c >= K_NN && c <= SELWIN) { tcut = tm; conv = true; }
                else if (c < K_NN) lo = mid;
                else hi = mid;
                if (hi - lo <= 1u) break;
            }
        }

        int run = 0;
        #pragma unroll
        for (int r = 0; r < 12; ++r) {
            bool p = key[r] < tcut;
            unsigned long long mask = __ballot(p);
            if (p) {
                int q = run + (int)__popcll(mask & ((1ull << lane) - 1ull));
                skeys[wv][q] = key[r];
            }
            run += (int)__popcll(mask);
        }
        nsel = run;
    } else {
        // ---- slow path (rare/flagged): wave-local global repair ----
        unsigned tb = __float_as_uint(tws[bm]);
        unsigned lo = 0, hi = 0x7F000000u, good = 0;
        bool haveLo = false, haveHi = false;
        if (cnt < K_NN) { lo = tb; haveLo = true; }
        else            { hi = tb; haveHi = true; }
        unsigned cur = tb;
        for (int a = 0; a < 40 && !good; ++a) {
            if (haveLo && !haveHi) {
                cur = (cur < 0x7E800000u) ? cur + 0x00800000u : 0x7F000000u;
            } else if (haveHi && !haveLo) {
                cur = (cur >= 0x00800000u) ? cur - 0x00800000u : (cur >> 1);
            } else {
                cur = lo + ((hi - lo) >> 1);
                if (hi - lo <= 1u) { good = hi; break; }
            }
            float tf = __uint_as_float(cur);
            int c = 0;
            for (int i0 = lane; i0 < N_PTS; i0 += 64) {
                float dx = pts[i0 * 3 + 0] - nx;
                float dy = pts[i0 * 3 + 1] - ny;
                float dz = pts[i0 * 3 + 2] - nz;
                c += (int)(dx * dx + dy * dy + dz * dz < tf);
            }
            for (int off = 32; off; off >>= 1) c += __shfl_down(c, off);
            c = __shfl(c, 0);
            if (c >= K_NN && c <= CAP) good = cur;
            else if (c < K_NN) { lo = cur; haveLo = true; }
            else               { hi = cur; haveHi = true; }
        }
        if (!good) good = haveHi ? hi : 0x7F000000u;
        int run = 0;
        for (int base = 0; base < N_PTS; base += 64) {
            int i0 = base + lane;
            bool pred = false;
            unsigned kb2 = 0;
            if (i0 < N_PTS) { kb2 = d2bits(i0); pred = kb2 < good; }
            unsigned long long mask = __ballot(pred);
            if (pred) {
                int q = run + (int)__popcll(mask & ((1ull << lane) - 1ull));
                if (q < CAP)
                    skeys[wv][q] = ((unsigned long long)kb2 << 32) | (unsigned int)i0;
            }
            run += (int)__popcll(mask);
        }
        nsel = run < CAP ? run : CAP;
    }
    __syncthreads();

    // ---- exact rank selection of the 50 nearest (ties -> low idx) ----
    for (int s = lane; s < nsel; s += 64) {
        unsigned long long mk = skeys[wv][s];
        int rank = 0;
        for (int j = 0; j < nsel; ++j) rank += (int)(skeys[wv][j] < mk);
        if (rank < K_NN) selidx[wv][rank] = (unsigned short)mk;  // idx < 65536
    }
    __syncthreads();

    // ---- PPF features (one neighbor per lane) ----
    if (lane < K_NN) {
        int i = (int)selidx[wv][lane];
        float pxx = pts[i * 3 + 0], pyy = pts[i * 3 + 1], pzz = pts[i * 3 + 2];
        float qx = pnr[i * 3 + 0], qy = pnr[i * 3 + 1], qz = pnr[i * 3 + 2];
        float ijx = pxx - nx, ijy = pyy - ny, ijz = pzz - nz;
        float d = sqrtf(ijx * ijx + ijy * ijy + ijz * ijz);
        f4v[wv][lane] = make_float4(d,
                                    signed_angle(ijx, ijy, ijz, n1x, n1y, n1z),
                                    signed_angle(-ijx, -ijy, -ijz, qx, qy, qz),
                                    signed_angle(n1x, n1y, n1z, qx, qy, qz));
    }
    __syncthreads();

    // ---- glob[d] = max_k (f4[k] . W[:,d]) + b[d] ; 4 dims per lane ----
    {
        float w0[4], w1[4], w2[4], w3[4], bb[4], mx[4];
        #pragma unroll
        for (int q = 0; q < 4; ++q) {
            int d = lane + 64 * q;
            w0[q] = W[d]; w1[q] = W[D_MODEL + d];
            w2[q] = W[2 * D_MODEL + d]; w3[q] = W[3 * D_MODEL + d];
            bb[q] = bias[d]; mx[q] = -INFINITY;
        }
        #pragma unroll 5
        for (int k = 0; k < K_NN; ++k) {
            float4 f = f4v[wv][k];
            #pragma unroll
            for (int q = 0; q < 4; ++q)
                mx[q] = fmaxf(mx[q], f.x * w0[q] + f.y * w1[q] + f.z * w2[q] + f.w * w3[q]);
        }
        #pragma unroll
        for (int q = 0; q < 4; ++q)
            out[(size_t)bm * D_MODEL + lane + 64 * q] = mx[q] + bb[q];
    }
}

extern "C" void kernel_launch(void* const* d_in, const int* in_sizes, int n_in,
                              void* d_out, int out_size, void* d_ws, size_t ws_size,
                              hipStream_t stream) {
    const float* points = (const float*)d_in[0];
    const float* nodes  = (const float*)d_in[1];
    const float* pn     = (const float*)d_in[2];
    const float* nn     = (const float*)d_in[3];
    const float* W      = (const float*)d_in[4];
    const float* bias   = (const float*)d_in[5];
    float* out = (float*)d_out;

    // ws layout: tws f32[4096] @0 ; gcount i32[4096] @16K ; cand u16[4096*768] @32K
    char* ws = (char*)d_ws;
    float* tws = (float*)ws;
    int* gcount = (int*)(ws + 16384);
    unsigned short* cand = (unsigned short*)(ws + 32768);

    ka_thresh<<<dim3(NNODE / 4), dim3(256), 0, stream>>>(points, nodes, tws, gcount, out);
    kb_scan<<<dim3(NNODE / TN, KB_NCHUNK), dim3(256), 0, stream>>>(points, nodes, tws, gcount, cand);
    kc_select<<<dim3(NNODE / 4), dim3(256), 0, stream>>>(points, nodes, pn, nn, W, bias,
                                                         tws, gcount, cand, out);
}